// Round 1
// baseline (433.454 us; speedup 1.0000x reference)
//
#include <hip/hip_runtime.h>

#define T_LEN 256
#define K 16
#define B_TOT 8192
#define RSCALE 3.2734375f  // fixed per-step log-scale removal; exact value uncritical (renorm covers drift)

__device__ __forceinline__ float ror1(float x) {
    int xi = __float_as_int(x);
    // DPP ROW_ROR:1 (0x121), all rows/banks enabled
    int r = __builtin_amdgcn_update_dpp(xi, xi, 0x121, 0xF, 0xF, false);
    return __int_as_float(r);
}

__global__ __launch_bounds__(256) void crf_fwd(
    const float* __restrict__ emissions,     // [B,T,K]
    const int*   __restrict__ tags,          // [B,T]
    const int*   __restrict__ who2who,       // [B,T-1]
    const int*   __restrict__ init_count,    // [B,T-1]
    const int*   __restrict__ distance,      // [B,T-1]
    const float* __restrict__ class_weights, // [K]
    const float* __restrict__ trans_stack,   // [4,K,K]
    const float* __restrict__ start_scores,  // [K]
    float*       __restrict__ out)           // [2*B]: gold then log_Z
{
    __shared__ float trans_lds[4 * K * K];
    for (int idx = threadIdx.x; idx < 4 * K * K; idx += blockDim.x)
        trans_lds[idx] = trans_stack[idx];
    __syncthreads();

    const int lane = threadIdx.x & 63;
    const int j    = lane & 15;                                   // state index within group
    const int seq  = (blockIdx.x * blockDim.x + threadIdx.x) >> 4; // 16 lanes per sequence

    // ---- probe DPP rotation direction (correct for either ROR convention) ----
    int pr    = __builtin_amdgcn_update_dpp(j, j, 0x121, 0xF, 0xF, false);
    int delta = (pr - j) & 15;  // after r rotations, lane j holds value from lane (j + r*delta)&15

    // ---- per-lane circulant diagonals of exp(trans): D[c][r] = exp(T_c[(j+r*delta)&15][j]) ----
    float D[4][16];
#pragma unroll
    for (int c = 0; c < 4; ++c) {
#pragma unroll
        for (int r = 0; r < 16; ++r) {
            int row = (j + r * delta) & 15;
            D[c][r] = __expf(trans_lds[c * 256 + row * 16 + j]);
        }
    }

    const float cw_j    = class_weights[j];
    const float start_j = start_scores[j];

    const float* em_ptr  = emissions + seq * (T_LEN * K) + j;
    const int*   tag_ptr = tags       + seq * T_LEN;
    const int*   w2w_ptr = who2who    + seq * (T_LEN - 1);
    const int*   ic_ptr  = init_count + seq * (T_LEN - 1);
    const int*   ds_ptr  = distance   + seq * (T_LEN - 1);

    // ---- t = 0 ----
    float em_cur   = em_ptr[0];
    int   tag_prev = tag_ptr[0];
    float u    = __expf(start_j + em_cur);          // u_0 = exp(alpha_0)
    float gold = (j == tag_prev) ? cw_j * (start_j + em_cur) : 0.0f;
    float logC = 0.0f;

    float em_next = em_ptr[K];  // prefetch t=1

    for (int t = 1; t < T_LEN; ++t) {
        em_cur = em_next;
        int tn = (t + 1 < T_LEN) ? (t + 1) : (T_LEN - 1);
        em_next = em_ptr[tn * K];  // software prefetch one step ahead

        int w2w  = w2w_ptr[t - 1];
        int ic   = ic_ptr[t - 1];
        int dist = ds_ptr[t - 1];
        int tag_cur = tag_ptr[t];
        int tidx = (w2w == 1) ? 0 : ((ic == 0) ? 1 : ((dist == 0) ? 2 : 3));
        bool tlo = tidx < 2, is0 = tidx == 0, is2 = tidx == 2;

        // ---- matvec via DPP rotation: s_j = sum_i u_i * E[tidx][i][j] ----
        float s = 0.0f, ur = u;
#pragma unroll
        for (int r = 0; r < 16; ++r) {
            if (r) ur = ror1(ur);
            float e = tlo ? (is0 ? D[0][r] : D[1][r])
                          : (is2 ? D[2][r] : D[3][r]);
            s = fmaf(ur, e, s);
        }

        // emission + fixed rescale
        u = s * __expf(em_cur - RSCALE);

        // ---- gold: lane j == tag_cur holds em_gold and the needed trans column entry ----
        float trg = trans_lds[tidx * 256 + tag_prev * 16 + j];
        if (j == tag_cur) gold = fmaf(cw_j, trg + em_cur, gold);
        tag_prev = tag_cur;

        // ---- exact power-of-2 renorm every 16 steps (overflow safety) ----
        if ((t & 15) == 0) {
            float mx = u;
#pragma unroll
            for (int m = 1; m < 16; m <<= 1)
                mx = fmaxf(mx, __shfl_xor(mx, m, 64));
            int ex;
            (void)frexpf(mx, &ex);
            u = ldexpf(u, -ex);
            logC += (float)ex * 0.693147180559945f;
        }
    }

    // ---- reduce across the 16-lane group ----
    float su = u, sg = gold;
#pragma unroll
    for (int m = 1; m < 16; m <<= 1) {
        su += __shfl_xor(su, m, 64);
        sg += __shfl_xor(sg, m, 64);
    }

    if (j == 0) {
        out[seq]          = sg;
        out[B_TOT + seq]  = logf(su) + 255.0f * RSCALE + logC;
    }
}

extern "C" void kernel_launch(void* const* d_in, const int* in_sizes, int n_in,
                              void* d_out, int out_size, void* d_ws, size_t ws_size,
                              hipStream_t stream) {
    const float* emissions     = (const float*)d_in[0];
    const int*   tags          = (const int*)  d_in[1];
    const int*   who2who       = (const int*)  d_in[2];
    const int*   init_count    = (const int*)  d_in[3];
    const int*   distance      = (const int*)  d_in[4];
    const float* class_weights = (const float*)d_in[5];
    const float* trans_stack   = (const float*)d_in[6];
    const float* start_scores  = (const float*)d_in[7];
    float* out = (float*)d_out;

    dim3 grid(B_TOT * 16 / 256);  // 512 blocks
    dim3 block(256);
    hipLaunchKernelGGL(crf_fwd, grid, block, 0, stream,
                       emissions, tags, who2who, init_count, distance,
                       class_weights, trans_stack, start_scores, out);
}

// Round 2
// 273.186 us; speedup vs baseline: 1.5867x; 1.5867x over previous
//
#include <hip/hip_runtime.h>

#define T_LEN 256
#define K 16
#define B_TOT 8192
#define RSCALE 3.2734375f

// ---------------- pack kernel: per (b,t) control byte + gold transition term ----------------
// ctrl[b][t]  = tag(4b) | tidx<<4           (tidx=0 for t=0, unused)
// goldt[b][t] = cw[tag_t] * trans[tidx][tag_{t-1}][tag_t]   (0 for t=0)
__global__ __launch_bounds__(256) void pack_ctrl(
    const int* __restrict__ tags, const int* __restrict__ w2w,
    const int* __restrict__ ic,   const int* __restrict__ ds,
    const float* __restrict__ cw, const float* __restrict__ trans,
    unsigned char* __restrict__ ctrl, float* __restrict__ goldt)
{
    int idx = blockIdx.x * 256 + threadIdx.x;      // b*256 + t
    int b = idx >> 8, t = idx & 255;
    int tag = tags[idx];
    unsigned char byte = (unsigned char)tag;
    float g = 0.0f;
    if (t > 0) {
        int off = b * (T_LEN - 1) + (t - 1);
        int tidx = (w2w[off] == 1) ? 0 : ((ic[off] == 0) ? 1 : ((ds[off] == 0) ? 2 : 3));
        byte |= (unsigned char)(tidx << 4);
        int tp = tags[idx - 1];
        g = cw[tag] * trans[tidx * 256 + tp * 16 + tag];
    }
    ctrl[idx]  = byte;
    goldt[idx] = g;
}

// ---------------- main kernel ----------------
__device__ __forceinline__ float ror1(float x) {
    int xi = __float_as_int(x);
    int r = __builtin_amdgcn_update_dpp(xi, xi, 0x121, 0xF, 0xF, false); // ROW_ROR:1
    return __int_as_float(r);
}
__device__ __forceinline__ float ror8(float x) {
    int xi = __float_as_int(x);
    int r = __builtin_amdgcn_update_dpp(xi, xi, 0x128, 0xF, 0xF, false); // ROW_ROR:8
    return __int_as_float(r);
}

__global__ __launch_bounds__(256, 2) void crf_fwd(
    const float* __restrict__ emissions,     // [B,T,K]
    const float* __restrict__ class_weights, // [K]
    const float* __restrict__ trans_stack,   // [4,K,K]
    const float* __restrict__ start_scores,  // [K]
    const uint4* __restrict__ ctrl16,        // [B,16] 16 ctrl bytes per block
    const float4* __restrict__ goldt4,       // [B,64] gold terms, 4 per float4
    float*       __restrict__ out)           // [2*B]
{
    __shared__ float trans_lds[4 * K * K];
    for (int idx = threadIdx.x; idx < 4 * K * K; idx += blockDim.x)
        trans_lds[idx] = trans_stack[idx];
    __syncthreads();

    const int j   = threadIdx.x & 15;
    const int seq = (blockIdx.x * blockDim.x + threadIdx.x) >> 4;

    // DPP rotation direction probe
    int pr    = __builtin_amdgcn_update_dpp(j, j, 0x121, 0xF, 0xF, false);
    int delta = (pr - j) & 15;

    // circulant diagonals of exp(trans): D[c][r] = exp(T_c[(j+r*delta)&15][j])
    float D[4][16];
#pragma unroll
    for (int c = 0; c < 4; ++c)
#pragma unroll
        for (int r = 0; r < 16; ++r)
            D[c][r] = __expf(trans_lds[c * 256 + ((j + r * delta) & 15) * 16 + j]);

    const float cw_j    = class_weights[j];
    const float start_j = start_scores[j];
    const float* em_ptr = emissions + seq * (T_LEN * K) + j;

    float u = 0.0f, gold = 0.0f, logC = 0.0f;

    // ---- preload block 0 ----
    float emb[16];
#pragma unroll
    for (int k = 0; k < 16; ++k) emb[k] = em_ptr[k * K];
    uint4 pkt = ctrl16[seq * 16 + 0];
    float gtf[16];
    {
        float4 q0 = goldt4[seq * 64 + 0], q1 = goldt4[seq * 64 + 1];
        float4 q2 = goldt4[seq * 64 + 2], q3 = goldt4[seq * 64 + 3];
        gtf[0]=q0.x; gtf[1]=q0.y; gtf[2]=q0.z; gtf[3]=q0.w;
        gtf[4]=q1.x; gtf[5]=q1.y; gtf[6]=q1.z; gtf[7]=q1.w;
        gtf[8]=q2.x; gtf[9]=q2.y; gtf[10]=q2.z; gtf[11]=q2.w;
        gtf[12]=q3.x; gtf[13]=q3.y; gtf[14]=q3.z; gtf[15]=q3.w;
    }

    for (int blk = 0; blk < 16; ++blk) {
        // ---- prefetch next block (clamped; issued early, consumed after 16 steps) ----
        int nb = (blk < 15) ? blk + 1 : 15;
        float embn[16];
#pragma unroll
        for (int k = 0; k < 16; ++k) embn[k] = em_ptr[(nb * 16 + k) * K];
        uint4 pktn = ctrl16[seq * 16 + nb];
        float4 q0 = goldt4[seq * 64 + nb * 4 + 0], q1 = goldt4[seq * 64 + nb * 4 + 1];
        float4 q2 = goldt4[seq * 64 + nb * 4 + 2], q3 = goldt4[seq * 64 + nb * 4 + 3];

        // ---- process 16 steps from registers ----
#pragma unroll
        for (int k = 0; k < 16; ++k) {
            unsigned w = (k < 4) ? pkt.x : (k < 8) ? pkt.y : (k < 12) ? pkt.z : pkt.w;
            unsigned byte = (w >> (8 * (k & 3))) & 0xFFu;
            int tag  = (int)(byte & 15u);
            int tidx = (int)(byte >> 4);

            if (blk == 0 && k == 0) {
                u    = __expf(start_j + emb[0]);
                gold = (j == tag) ? cw_j * (start_j + emb[0]) : 0.0f;
            } else {
                bool tlo = tidx < 2, is0 = tidx == 0, is2 = tidx == 2;
                float s0 = 0.0f, s1 = 0.0f;
                float ua = u, ub = ror8(u);
#pragma unroll
                for (int r = 0; r < 8; ++r) {
                    if (r) { ua = ror1(ua); ub = ror1(ub); }
                    float e0a = is0 ? D[0][r] : D[1][r];
                    float e0b = is2 ? D[2][r] : D[3][r];
                    float e0  = tlo ? e0a : e0b;
                    float e1a = is0 ? D[0][r + 8] : D[1][r + 8];
                    float e1b = is2 ? D[2][r + 8] : D[3][r + 8];
                    float e1  = tlo ? e1a : e1b;
                    s0 = fmaf(ua, e0, s0);
                    s1 = fmaf(ub, e1, s1);
                }
                u = (s0 + s1) * __expf(emb[k] - RSCALE);
                if (j == tag) gold += gtf[k] + cw_j * emb[k];
            }
        }

        // ---- exact power-of-2 renorm once per block ----
        {
            float mx = u;
#pragma unroll
            for (int m = 1; m < 16; m <<= 1)
                mx = fmaxf(mx, __shfl_xor(mx, m, 64));
            int ex;
            (void)frexpf(mx, &ex);
            u = ldexpf(u, -ex);
            logC += (float)ex * 0.693147180559945f;
        }

        // ---- rotate buffers ----
#pragma unroll
        for (int k = 0; k < 16; ++k) emb[k] = embn[k];
        pkt = pktn;
        gtf[0]=q0.x; gtf[1]=q0.y; gtf[2]=q0.z; gtf[3]=q0.w;
        gtf[4]=q1.x; gtf[5]=q1.y; gtf[6]=q1.z; gtf[7]=q1.w;
        gtf[8]=q2.x; gtf[9]=q2.y; gtf[10]=q2.z; gtf[11]=q2.w;
        gtf[12]=q3.x; gtf[13]=q3.y; gtf[14]=q3.z; gtf[15]=q3.w;
    }

    // ---- reduce across the 16-lane group ----
    float su = u, sg = gold;
#pragma unroll
    for (int m = 1; m < 16; m <<= 1) {
        su += __shfl_xor(su, m, 64);
        sg += __shfl_xor(sg, m, 64);
    }

    if (j == 0) {
        out[seq]         = sg;
        out[B_TOT + seq] = logf(su) + 255.0f * RSCALE + logC;
    }
}

extern "C" void kernel_launch(void* const* d_in, const int* in_sizes, int n_in,
                              void* d_out, int out_size, void* d_ws, size_t ws_size,
                              hipStream_t stream) {
    const float* emissions     = (const float*)d_in[0];
    const int*   tags          = (const int*)  d_in[1];
    const int*   who2who       = (const int*)  d_in[2];
    const int*   init_count    = (const int*)  d_in[3];
    const int*   distance      = (const int*)  d_in[4];
    const float* class_weights = (const float*)d_in[5];
    const float* trans_stack   = (const float*)d_in[6];
    const float* start_scores  = (const float*)d_in[7];
    float* out = (float*)d_out;

    unsigned char* ctrl  = (unsigned char*)d_ws;                    // 2 MB
    float*         goldt = (float*)((char*)d_ws + B_TOT * T_LEN);   // 8 MB

    hipLaunchKernelGGL(pack_ctrl, dim3(B_TOT), dim3(256), 0, stream,
                       tags, who2who, init_count, distance,
                       class_weights, trans_stack, ctrl, goldt);

    hipLaunchKernelGGL(crf_fwd, dim3(B_TOT * 16 / 256), dim3(256), 0, stream,
                       emissions, class_weights, trans_stack, start_scores,
                       (const uint4*)ctrl, (const float4*)goldt, out);
}